// Round 6
// baseline (400.523 us; speedup 1.0000x reference)
//
#include <hip/hip_runtime.h>
#include <stdint.h>

#define IMG 28
#define OD 26
#define K_REAL 784
#define N_REAL 300
#define KPAD 800
#define NPAD 320
#define NT 20      // N tiles of 16
#define NKS 25     // K steps of 32
#define KS2N 10    // GEMM2 K steps (320/32)
#define BM 16      // rows per block (1 wave per block)
#define THREADS 64

typedef float f32x4 __attribute__((ext_vector_type(4)));
typedef short s16x8 __attribute__((ext_vector_type(8)));

__device__ __forceinline__ unsigned short f2bf(float f) {
  union { float f; uint32_t u; } v; v.f = f;
  uint32_t u = v.u;
  return (unsigned short)((u + 0x7fffu + ((u >> 16) & 1u)) >> 16);  // RNE
}

// pack 8 f32 -> 8 bf16 (RNE) via v_cvt_pk_bf16_f32 (no builtin on gfx950)
__device__ __forceinline__ s16x8 cvt8(f32x4 a, f32x4 b) {
  union { uint32_t u[4]; s16x8 v; } r;
  asm("v_cvt_pk_bf16_f32 %0, %1, %2" : "=v"(r.u[0]) : "v"(a[0]), "v"(a[1]));
  asm("v_cvt_pk_bf16_f32 %0, %1, %2" : "=v"(r.u[1]) : "v"(a[2]), "v"(a[3]));
  asm("v_cvt_pk_bf16_f32 %0, %1, %2" : "=v"(r.u[2]) : "v"(b[0]), "v"(b[1]));
  asm("v_cvt_pk_bf16_f32 %0, %1, %2" : "=v"(r.u[3]) : "v"(b[2]), "v"(b[3]));
  return r.v;
}

// ---------------- pack Weff = C^T * w1  into MFMA-B fragment order ----------
// layout: [ks(25)][nt(20)][lane(64)][8] bf16, lane = g*16 + (col&15), elem = k&7
__global__ void pack_weff(const float* __restrict__ conv_w,
                          const float* __restrict__ w1,
                          unsigned short* __restrict__ weffp) {
  int t = blockIdx.x * blockDim.x + threadIdx.x;
  if (t >= KPAD * NPAD) return;
  int i = t / NPAD;        // k (input pixel) 0..799
  int j = t - i * NPAD;    // col 0..319
  float v = 0.f;
  if (i < K_REAL && j < N_REAL) {
    int r = i / IMG, c = i % IMG;
#pragma unroll
    for (int kh = 0; kh < 3; ++kh) {
      int orr = r - kh;
      if (orr < 0 || orr >= OD) continue;
#pragma unroll
      for (int kw = 0; kw < 3; ++kw) {
        int occ = c - kw;
        if (occ < 0 || occ >= OD) continue;
        v += conv_w[kh * 3 + kw] * w1[(orr * OD + occ) * N_REAL + j];
      }
    }
  }
  int ks = i >> 5, i5 = i & 31, g = i5 >> 3, jj = i5 & 7;
  int nt = j >> 4, c16 = j & 15;
  int lane = g * 16 + c16;
  weffp[(((size_t)ks * NT + nt) * 64 + lane) * 8 + jj] = f2bf(v);
}

// ---------------- pack w2 (300x10 -> 320x16) into fragment order ------------
__global__ void pack_w2(const float* __restrict__ w2,
                        unsigned short* __restrict__ w2p) {
  int t = blockIdx.x * blockDim.x + threadIdx.x;
  if (t >= 320 * 16) return;
  int k = t >> 4, j = t & 15;
  float v = (k < N_REAL && j < 10) ? w2[k * 10 + j] : 0.f;
  int ks = k >> 5, g = (k & 31) >> 3, jj = k & 7;
  w2p[((size_t)ks * 64 + g * 16 + j) * 8 + jj] = f2bf(v);
}

// ---------------- fused: relu(x @ Weff + b1) @ w2 + b2 ----------------------
// 1 wave per block, 16 rows x 320 cols per wave. Barrier-free: B fragments
// straight from global (Weff 512 KB, L2-resident); A prefetched 1 K-step
// ahead in registers. LDS only for the per-wave a1 transpose (GEMM2).
__global__ void __launch_bounds__(THREADS, 4)
fused_kernel(const float* __restrict__ x,
             const float* __restrict__ b1,
             const float* __restrict__ b2,
             const unsigned short* __restrict__ weffp,
             const unsigned short* __restrict__ w2p,
             float* __restrict__ out) {
  __shared__ unsigned short a1lds[16 * 328];   // 10496 B -> 15 blocks/CU

  const int lane = threadIdx.x & 63;
  const int g = lane >> 4;
  const int c16 = lane & 15;
  const long row0 = (long)blockIdx.x * BM;

  const float* xrow = x + (size_t)(row0 + c16) * K_REAL + g * 8;
  const s16x8* bfrag = (const s16x8*)weffp + lane;   // + ks*1280 + nt*64

  f32x4 acc[NT];
#pragma unroll
  for (int i = 0; i < NT; ++i) acc[i] = f32x4{0.f, 0.f, 0.f, 0.f};

  f32x4 a0n = *(const f32x4*)(xrow);
  f32x4 a1n = *(const f32x4*)(xrow + 4);

#pragma unroll 1
  for (int ks = 0; ks < NKS - 1; ++ks) {
    s16x8 af = cvt8(a0n, a1n);
    // prefetch next K-step's A (guard tail: ks+1==24 only valid for g<2)
    if (ks < NKS - 2 || g < 2) {
      a0n = *(const f32x4*)(xrow + (ks + 1) * 32);
      a1n = *(const f32x4*)(xrow + (ks + 1) * 32 + 4);
    }
    const s16x8* bp = bfrag + (size_t)ks * 1280;   // 20480 B / 16
#pragma unroll
    for (int nt = 0; nt < NT; ++nt) {
      s16x8 bfr = bp[nt * 64];
      acc[nt] = __builtin_amdgcn_mfma_f32_16x16x32_bf16(af, bfr, acc[nt], 0, 0, 0);
    }
  }
  {  // tail K-step ks=24: k = 768 + g*8 valid only for g<2 (784 real K)
    s16x8 af = s16x8{0, 0, 0, 0, 0, 0, 0, 0};
    if (g < 2) af = cvt8(a0n, a1n);
    const s16x8* bp = bfrag + (size_t)(NKS - 1) * 1280;
#pragma unroll
    for (int nt = 0; nt < NT; ++nt) {
      s16x8 bfr = bp[nt * 64];
      acc[nt] = __builtin_amdgcn_mfma_f32_16x16x32_bf16(af, bfr, acc[nt], 0, 0, 0);
    }
  }

  // epilogue: +b1, relu, a1 -> LDS bf16 (row stride 328 shorts, 656 B)
  unsigned short* a1w = a1lds;
  const int rbase = g * 4;
#pragma unroll
  for (int nt = 0; nt < NT; ++nt) {
    int col = nt * 16 + c16;
    float bias = (col < N_REAL) ? b1[col] : 0.f;
#pragma unroll
    for (int r = 0; r < 4; ++r) {
      float v = acc[nt][r] + bias;
      v = v > 0.f ? v : 0.f;
      a1w[(rbase + r) * 328 + col] = f2bf(v);
    }
  }

  // GEMM2: 16x16 out tile, K2 = 320 (w2p is L1/L2-resident)
  f32x4 acc2 = f32x4{0.f, 0.f, 0.f, 0.f};
#pragma unroll
  for (int ks2 = 0; ks2 < KS2N; ++ks2) {
    s16x8 a2 = *(const s16x8*)((const unsigned char*)a1w + c16 * 656 + ks2 * 64 + g * 16);
    s16x8 b2f = *(const s16x8*)(w2p + ((size_t)ks2 * 64 + lane) * 8);
    acc2 = __builtin_amdgcn_mfma_f32_16x16x32_bf16(a2, b2f, acc2, 0, 0, 0);
  }
  if (c16 < 10) {
    float bv = b2[c16];
#pragma unroll
    for (int r = 0; r < 4; ++r) {
      long grow = row0 + rbase + r;
      out[grow * 10 + c16] = acc2[r] + bv;
    }
  }
}

extern "C" void kernel_launch(void* const* d_in, const int* in_sizes, int n_in,
                              void* d_out, int out_size, void* d_ws, size_t ws_size,
                              hipStream_t stream) {
  const float* x      = (const float*)d_in[0];
  const float* conv_w = (const float*)d_in[1];
  const float* w1     = (const float*)d_in[2];
  const float* b1     = (const float*)d_in[3];
  const float* w2     = (const float*)d_in[4];
  const float* b2     = (const float*)d_in[5];
  float* out = (float*)d_out;
  const int B = in_sizes[0] / K_REAL;

  unsigned short* weffp = (unsigned short*)d_ws;                     // 512000 B
  unsigned short* w2p   = (unsigned short*)((char*)d_ws + 512000);   // 10240 B

  pack_weff<<<(KPAD * NPAD + 255) / 256, 256, 0, stream>>>(conv_w, w1, weffp);
  pack_w2<<<(320 * 16 + 255) / 256, 256, 0, stream>>>(w2, w2p);
  fused_kernel<<<B / BM, THREADS, 0, stream>>>(x, b1, b2, weffp, w2p, out);
}

// Round 7
// 304.614 us; speedup vs baseline: 1.3149x; 1.3149x over previous
//
#include <hip/hip_runtime.h>
#include <stdint.h>

#define IMG 28
#define OD 26
#define K_REAL 784
#define N_REAL 300
#define KPAD 800
#define NPAD 320
#define NT 20      // N tiles of 16
#define NKS 25     // K steps of 32
#define KS2N 10    // GEMM2 K steps (320/32)
#define BM 128     // rows per block (4 waves x 32 rows)
#define THREADS 256

typedef float f32x4 __attribute__((ext_vector_type(4)));
typedef short s16x8 __attribute__((ext_vector_type(8)));

__device__ __forceinline__ unsigned short f2bf(float f) {
  union { float f; uint32_t u; } v; v.f = f;
  uint32_t u = v.u;
  return (unsigned short)((u + 0x7fffu + ((u >> 16) & 1u)) >> 16);  // RNE
}

// pack 8 f32 -> 8 bf16 (RNE) via v_cvt_pk_bf16_f32 (no builtin on gfx950)
__device__ __forceinline__ s16x8 cvt8(f32x4 a, f32x4 b) {
  union { uint32_t u[4]; s16x8 v; } r;
  asm("v_cvt_pk_bf16_f32 %0, %1, %2" : "=v"(r.u[0]) : "v"(a[0]), "v"(a[1]));
  asm("v_cvt_pk_bf16_f32 %0, %1, %2" : "=v"(r.u[1]) : "v"(a[2]), "v"(a[3]));
  asm("v_cvt_pk_bf16_f32 %0, %1, %2" : "=v"(r.u[2]) : "v"(b[0]), "v"(b[1]));
  asm("v_cvt_pk_bf16_f32 %0, %1, %2" : "=v"(r.u[3]) : "v"(b[2]), "v"(b[3]));
  return r.v;
}

// ---------------- pack Weff = C^T * w1  into MFMA-B fragment order ----------
// layout: [ks(25)][nt(20)][lane(64)][8] bf16, lane = g*16 + (col&15), elem = k&7
__global__ void pack_weff(const float* __restrict__ conv_w,
                          const float* __restrict__ w1,
                          unsigned short* __restrict__ weffp) {
  int t = blockIdx.x * blockDim.x + threadIdx.x;
  if (t >= KPAD * NPAD) return;
  int i = t / NPAD;        // k (input pixel) 0..799
  int j = t - i * NPAD;    // col 0..319
  float v = 0.f;
  if (i < K_REAL && j < N_REAL) {
    int r = i / IMG, c = i % IMG;
#pragma unroll
    for (int kh = 0; kh < 3; ++kh) {
      int orr = r - kh;
      if (orr < 0 || orr >= OD) continue;
#pragma unroll
      for (int kw = 0; kw < 3; ++kw) {
        int occ = c - kw;
        if (occ < 0 || occ >= OD) continue;
        v += conv_w[kh * 3 + kw] * w1[(orr * OD + occ) * N_REAL + j];
      }
    }
  }
  int ks = i >> 5, i5 = i & 31, g = i5 >> 3, jj = i5 & 7;
  int nt = j >> 4, c16 = j & 15;
  int lane = g * 16 + c16;
  weffp[(((size_t)ks * NT + nt) * 64 + lane) * 8 + jj] = f2bf(v);
}

// ---------------- pack w2 (300x10 -> 320x16) into fragment order ------------
__global__ void pack_w2(const float* __restrict__ w2,
                        unsigned short* __restrict__ w2p) {
  int t = blockIdx.x * blockDim.x + threadIdx.x;
  if (t >= 320 * 16) return;
  int k = t >> 4, j = t & 15;
  float v = (k < N_REAL && j < 10) ? w2[k * 10 + j] : 0.f;
  int ks = k >> 5, g = (k & 31) >> 3, jj = k & 7;
  w2p[((size_t)ks * 64 + g * 16 + j) * 8 + jj] = f2bf(v);
}

// ---------------- fused: relu(x @ Weff + b1) @ w2 + b2 ----------------------
// 4 waves x 32 rows; B tile shared through LDS (global_load_lds, dbuf, one
// barrier per K-step, m97 structure). Each ds_read_b128 feeds 2 MFMAs.
// B L2 traffic: 512 blocks x 500 KB = 256 MB (vs 2 GB at 1-wave blocks).
__global__ void __launch_bounds__(THREADS, 2)
fused_kernel(const float* __restrict__ x,
             const float* __restrict__ b1,
             const float* __restrict__ b2,
             const unsigned short* __restrict__ weffp,
             const unsigned short* __restrict__ w2p,
             float* __restrict__ out) {
  __shared__ uint4 ldsq[41984 / 16];   // 2x20480 B-dbuf; reused as 4x10496 a1
  unsigned char* lds = (unsigned char*)ldsq;

  const int tid = threadIdx.x;
  const int wid = tid >> 6;
  const int lane = tid & 63;
  const int g = lane >> 4;
  const int c16 = lane & 15;
  const long row0w = (long)blockIdx.x * BM + wid * 32;

  const float* xb0 = x + (size_t)(row0w + c16) * K_REAL + g * 8;
  const float* xb1 = xb0 + (size_t)16 * K_REAL;

  f32x4 acc0[NT], acc1[NT];
#pragma unroll
  for (int i = 0; i < NT; ++i) {
    acc0[i] = f32x4{0.f, 0.f, 0.f, 0.f};
    acc1[i] = f32x4{0.f, 0.f, 0.f, 0.f};
  }

  // stage one 20 KB B-tile into LDS buffer sel; 5 x 16B chunks per thread,
  // linear: lds dest = uniform base + lane*16 (global_load_lds requirement)
#define STAGE(ks_, sel_)                                                        \
  {                                                                             \
    _Pragma("unroll")                                                           \
    for (int i_ = 0; i_ < 5; ++i_) {                                            \
      int off_ = i_ * 4096 + tid * 16;                                          \
      const unsigned char* gsrc_ = (const unsigned char*)weffp +                \
          (size_t)(ks_) * 20480 + off_;                                         \
      __builtin_amdgcn_global_load_lds(                                         \
          (const __attribute__((address_space(1))) uint32_t*)gsrc_,             \
          (__attribute__((address_space(3))) uint32_t*)&lds[(sel_) * 20480 + off_], \
          16, 0, 0);                                                            \
    }                                                                           \
  }

  STAGE(0, 0);
  f32x4 ar00 = *(const f32x4*)(xb0);
  f32x4 ar01 = *(const f32x4*)(xb0 + 4);
  f32x4 ar10 = *(const f32x4*)(xb1);
  f32x4 ar11 = *(const f32x4*)(xb1 + 4);

#pragma unroll 1
  for (int ks = 0; ks < NKS - 1; ++ks) {
    __syncthreads();                       // stage(ks) visible to all waves
    s16x8 af0 = cvt8(ar00, ar01);
    s16x8 af1 = cvt8(ar10, ar11);
    STAGE(ks + 1, (ks + 1) & 1);
    if (ks < NKS - 2 || g < 2) {           // tail k-step valid only for g<2
      ar00 = *(const f32x4*)(xb0 + (ks + 1) * 32);
      ar01 = *(const f32x4*)(xb0 + (ks + 1) * 32 + 4);
      ar10 = *(const f32x4*)(xb1 + (ks + 1) * 32);
      ar11 = *(const f32x4*)(xb1 + (ks + 1) * 32 + 4);
    }
    const unsigned char* bufc = &lds[(ks & 1) * 20480];
#pragma unroll
    for (int nt = 0; nt < NT; ++nt) {
      s16x8 bfr = *(const s16x8*)(bufc + nt * 1024 + lane * 16);
      acc0[nt] = __builtin_amdgcn_mfma_f32_16x16x32_bf16(af0, bfr, acc0[nt], 0, 0, 0);
      acc1[nt] = __builtin_amdgcn_mfma_f32_16x16x32_bf16(af1, bfr, acc1[nt], 0, 0, 0);
    }
  }
  {  // tail K-step ks=24 (tile staged into buf0): k=768+g*8 valid for g<2
    __syncthreads();
    s16x8 af0 = s16x8{0, 0, 0, 0, 0, 0, 0, 0};
    s16x8 af1 = s16x8{0, 0, 0, 0, 0, 0, 0, 0};
    if (g < 2) {
      af0 = cvt8(ar00, ar01);
      af1 = cvt8(ar10, ar11);
    }
    const unsigned char* bufc = &lds[0];
#pragma unroll
    for (int nt = 0; nt < NT; ++nt) {
      s16x8 bfr = *(const s16x8*)(bufc + nt * 1024 + lane * 16);
      acc0[nt] = __builtin_amdgcn_mfma_f32_16x16x32_bf16(af0, bfr, acc0[nt], 0, 0, 0);
      acc1[nt] = __builtin_amdgcn_mfma_f32_16x16x32_bf16(af1, bfr, acc1[nt], 0, 0, 0);
    }
  }
  __syncthreads();   // all B reads done everywhere; LDS reused for a1

  // epilogue per 16-row set: +b1, relu -> a1 in LDS (stride 328 shorts),
  // then GEMM2 (K2=320) and store. Per-wave private 10496 B region.
  unsigned short* a1w = (unsigned short*)(void*)&lds[wid * 10496];
  const int rbase = g * 4;
#pragma unroll
  for (int s = 0; s < 2; ++s) {
    const f32x4* accS = (s == 0) ? acc0 : acc1;
#pragma unroll
    for (int nt = 0; nt < NT; ++nt) {
      int col = nt * 16 + c16;
      float bias = (col < N_REAL) ? b1[col] : 0.f;
#pragma unroll
      for (int r = 0; r < 4; ++r) {
        float v = accS[nt][r] + bias;
        v = v > 0.f ? v : 0.f;
        a1w[(rbase + r) * 328 + col] = f2bf(v);
      }
    }
    f32x4 acc2 = f32x4{0.f, 0.f, 0.f, 0.f};
#pragma unroll
    for (int ks2 = 0; ks2 < KS2N; ++ks2) {
      s16x8 a2 = *(const s16x8*)((const unsigned char*)a1w + c16 * 656 + ks2 * 64 + g * 16);
      s16x8 b2f = *(const s16x8*)(w2p + ((size_t)ks2 * 64 + lane) * 8);
      acc2 = __builtin_amdgcn_mfma_f32_16x16x32_bf16(a2, b2f, acc2, 0, 0, 0);
    }
    if (c16 < 10) {
      float bv = b2[c16];
#pragma unroll
      for (int r = 0; r < 4; ++r) {
        long grow = row0w + s * 16 + rbase + r;
        out[grow * 10 + c16] = acc2[r] + bv;
      }
    }
  }
}

extern "C" void kernel_launch(void* const* d_in, const int* in_sizes, int n_in,
                              void* d_out, int out_size, void* d_ws, size_t ws_size,
                              hipStream_t stream) {
  const float* x      = (const float*)d_in[0];
  const float* conv_w = (const float*)d_in[1];
  const float* w1     = (const float*)d_in[2];
  const float* b1     = (const float*)d_in[3];
  const float* w2     = (const float*)d_in[4];
  const float* b2     = (const float*)d_in[5];
  float* out = (float*)d_out;
  const int B = in_sizes[0] / K_REAL;

  unsigned short* weffp = (unsigned short*)d_ws;                     // 512000 B
  unsigned short* w2p   = (unsigned short*)((char*)d_ws + 512000);   // 10240 B

  pack_weff<<<(KPAD * NPAD + 255) / 256, 256, 0, stream>>>(conv_w, w1, weffp);
  pack_w2<<<(320 * 16 + 255) / 256, 256, 0, stream>>>(w2, w2p);
  fused_kernel<<<B / BM, THREADS, 0, stream>>>(x, b1, b2, weffp, w2p, out);
}